// Round 6
// baseline (489.072 us; speedup 1.0000x reference)
//
#include <hip/hip_runtime.h>

// N=65536, D_OUT=128, D_LAT=64, D_Z=64. Streaming multi-reduction.
// R5 lessons: NT loads -> ~33us main kernel; total time is dominated by the
// harness's 256MiB d_ws poison fills (~115us fixed, 80% HBM peak).
// R6: hoist all loads (max MLP), fuse finalize via ticket, shrink memset.
constexpr int N_ROWS  = 65536;
constexpr int THREADS = 256;
constexpr int B_MSE = 1024, B_KL = 512, B_Z = 512;
constexpr int BLOCKS = B_MSE + B_KL + B_Z;      // 2048
constexpr int F4_BLK = 2048;                    // float4s per block per array
constexpr int IT     = F4_BLK / THREADS;        // 8 iters/thread

constexpr int NREP  = 64;                       // Z replicas: contention 512/64 = 8
constexpr int NZVAL = 320;                      // 5 stats x 64 cols
// ws layout (floats):
//   [r*NZVAL + v]        r in [0,64): Z replica accumulators (memset 0)
//   [TICKET]             ticket counter (memset 0)
//   [MSE_OFF + b]        per-block MSE partial, b in [0,1024) (plain store)
//   [KL_OFF + i]         per-block KL partial, i in [0,512)  (plain store)
constexpr int TICKET  = NREP * NZVAL;           // 20480
constexpr int MSE_OFF = TICKET + 1;             // 20481
constexpr int KL_OFF  = MSE_OFF + B_MSE;        // 21505
constexpr int MEMSET_BYTES = (TICKET + 1) * 4;  // replicas + ticket

typedef float f4v __attribute__((ext_vector_type(4)));

__device__ __forceinline__ f4v ntload(const f4v* p) {
    return __builtin_nontemporal_load(p);
}
__device__ __forceinline__ float agent_load(const float* p) {
    return __hip_atomic_load(p, __ATOMIC_RELAXED, __HIP_MEMORY_SCOPE_AGENT);
}
__device__ __forceinline__ void agent_store(float* p, float v) {
    __hip_atomic_store(p, v, __ATOMIC_RELAXED, __HIP_MEMORY_SCOPE_AGENT);
}

__global__ __launch_bounds__(THREADS) void vde_fused(
    const f4v* __restrict__ target,
    const f4v* __restrict__ output,
    const f4v* __restrict__ mean,
    const f4v* __restrict__ logvar,
    const f4v* __restrict__ zt,
    const f4v* __restrict__ ztau,
    float* __restrict__ ws,
    float* __restrict__ out)
{
    const int lane = threadIdx.x & 63;
    const int wave = threadIdx.x >> 6;

    __shared__ float ssc[4];                 // scalar cross-wave (MSE/KL)
    __shared__ float sred[4][16][20];        // column stats cross-wave (Z)

    if (blockIdx.x < B_MSE) {
        // ---------------- MSE: sum (o - t)^2 ------------------------------
        const int base = blockIdx.x * F4_BLK + threadIdx.x;
        f4v o[IT], t[IT];
        #pragma unroll
        for (int it = 0; it < IT; ++it) o[it] = ntload(&output[base + it * THREADS]);
        #pragma unroll
        for (int it = 0; it < IT; ++it) t[it] = ntload(&target[base + it * THREADS]);
        float recon = 0.f;
        #pragma unroll
        for (int it = 0; it < IT; ++it) {
            f4v d = o[it] - t[it];
            recon += d[0]*d[0] + d[1]*d[1] + d[2]*d[2] + d[3]*d[3];
        }
        #pragma unroll
        for (int m = 32; m >= 1; m >>= 1) recon += __shfl_xor(recon, m);
        if (lane == 0) ssc[wave] = recon;
        __syncthreads();
        if (threadIdx.x == 0)
            agent_store(&ws[MSE_OFF + blockIdx.x], ssc[0] + ssc[1] + ssc[2] + ssc[3]);

    } else if (blockIdx.x < B_MSE + B_KL) {
        // ---------------- KL: sum (lv - e^lv - m^2 + 1) -------------------
        const int bi = blockIdx.x - B_MSE;
        const int base = bi * F4_BLK + threadIdx.x;
        f4v lv[IT], mm[IT];
        #pragma unroll
        for (int it = 0; it < IT; ++it) lv[it] = ntload(&logvar[base + it * THREADS]);
        #pragma unroll
        for (int it = 0; it < IT; ++it) mm[it] = ntload(&mean[base + it * THREADS]);
        float kls = 0.f;
        #pragma unroll
        for (int it = 0; it < IT; ++it) {
            kls += (lv[it][0] - __expf(lv[it][0]) - mm[it][0]*mm[it][0] + 1.f)
                 + (lv[it][1] - __expf(lv[it][1]) - mm[it][1]*mm[it][1] + 1.f)
                 + (lv[it][2] - __expf(lv[it][2]) - mm[it][2]*mm[it][2] + 1.f)
                 + (lv[it][3] - __expf(lv[it][3]) - mm[it][3]*mm[it][3] + 1.f);
        }
        #pragma unroll
        for (int m = 32; m >= 1; m >>= 1) kls += __shfl_xor(kls, m);
        if (lane == 0) ssc[wave] = kls;
        __syncthreads();
        if (threadIdx.x == 0)
            agent_store(&ws[KL_OFF + bi], ssc[0] + ssc[1] + ssc[2] + ssc[3]);

    } else {
        // ---------------- Z column stats ----------------------------------
        // f = zb*2048 + it*256 + tid -> f%16 == tid%16: each thread owns the
        // fixed 4-column group g = tid&15 (cols 4g..4g+3).
        const int zi = blockIdx.x - B_MSE - B_KL;
        const int base = zi * F4_BLK + threadIdx.x;
        f4v a[IT], b[IT];
        #pragma unroll
        for (int it = 0; it < IT; ++it) a[it] = ntload(&zt[base + it * THREADS]);
        #pragma unroll
        for (int it = 0; it < IT; ++it) b[it] = ntload(&ztau[base + it * THREADS]);
        float s_t[4] = {0,0,0,0}, s_t2[4] = {0,0,0,0};
        float s_a[4] = {0,0,0,0}, s_a2[4] = {0,0,0,0}, s_c[4] = {0,0,0,0};
        #pragma unroll
        for (int it = 0; it < IT; ++it) {
            #pragma unroll
            for (int e = 0; e < 4; ++e) {
                s_t[e]  += a[it][e];          s_a[e]  += b[it][e];
                s_t2[e] += a[it][e]*a[it][e]; s_a2[e] += b[it][e]*b[it][e];
                s_c[e]  += a[it][e]*b[it][e];
            }
        }
        float vals[20];
        #pragma unroll
        for (int e = 0; e < 4; ++e) {
            vals[e*5+0] = s_t[e];  vals[e*5+1] = s_a[e];
            vals[e*5+2] = s_t2[e]; vals[e*5+3] = s_a2[e];
            vals[e*5+4] = s_c[e];
        }
        #pragma unroll
        for (int v = 0; v < 20; ++v) {
            vals[v] += __shfl_xor(vals[v], 16);
            vals[v] += __shfl_xor(vals[v], 32);
        }
        if (lane < 16) {
            #pragma unroll
            for (int v = 0; v < 20; ++v) sred[wave][lane][v] = vals[v];
        }
        __syncthreads();
        float* rep = ws + (zi & (NREP - 1)) * NZVAL;
        for (int i = threadIdx.x; i < 320; i += THREADS) {
            const int g = i / 20, v = i % 20;
            const float s = sred[0][g][v] + sred[1][g][v]
                          + sred[2][g][v] + sred[3][g][v];
            const int e = v / 5, st = v % 5;
            atomicAdd(&rep[st * 64 + (g * 4 + e)], s);
        }
    }

    // ---- last-block ticket -> fused finalize (R2-proven pattern) ----
    __shared__ unsigned s_last;
    __threadfence();                         // release our stores/atomics
    if (threadIdx.x == 0) {
        unsigned* ticket = (unsigned*)&ws[TICKET];
        s_last = (atomicAdd(ticket, 1u) == (unsigned)(BLOCKS - 1));
    }
    __syncthreads();
    if (!s_last) return;
    __threadfence();                         // acquire all blocks' results

    // collapse Z replicas: value v summed over 64 replicas (coalesced in v)
    __shared__ float zsums[NZVAL];
    for (int v = threadIdx.x; v < NZVAL; v += THREADS) {
        float s = 0.f;
        #pragma unroll 8
        for (int r = 0; r < NREP; ++r) s += agent_load(&ws[r * NZVAL + v]);
        zsums[v] = s;
    }
    // collapse MSE / KL per-block partials
    float rsum = 0.f;
    for (int i = threadIdx.x; i < B_MSE; i += THREADS) rsum += agent_load(&ws[MSE_OFF + i]);
    float ksum = 0.f;
    for (int i = threadIdx.x; i < B_KL; i += THREADS) ksum += agent_load(&ws[KL_OFF + i]);
    #pragma unroll
    for (int m = 32; m >= 1; m >>= 1) {
        rsum += __shfl_xor(rsum, m);
        ksum += __shfl_xor(ksum, m);
    }
    __shared__ float sc2[4][2];
    if (lane == 0) { sc2[wave][0] = rsum; sc2[wave][1] = ksum; }
    __syncthreads();

    if (threadIdx.x < 64) {
        const int j = threadIdx.x;          // column 0..63
        const float Nf = (float)N_ROWS;
        const float sum_t  = zsums[0*64 + j];
        const float sum_a  = zsums[1*64 + j];
        const float sum_t2 = zsums[2*64 + j];
        const float sum_a2 = zsums[3*64 + j];
        const float sum_c  = zsums[4*64 + j];

        const float mu_t = sum_t / Nf, mu_a = sum_a / Nf;
        float diag = sum_c - Nf * mu_t * mu_a;
        const float var_t = (sum_t2 - Nf * mu_t * mu_t) / (Nf - 1.f);
        const float var_a = (sum_a2 - Nf * mu_a * mu_a) / (Nf - 1.f);
        float sp = sqrtf(var_t) * sqrtf(var_a);

        #pragma unroll
        for (int m = 32; m >= 1; m >>= 1) {
            diag += __shfl_xor(diag, m);
            sp   += __shfl_xor(sp, m);
        }
        if (j == 0) {
            const float recon_f = (sc2[0][0] + sc2[1][0] + sc2[2][0] + sc2[3][0]) / (Nf * 128.f);
            const float kl_f    = -0.5f * (sc2[0][1] + sc2[1][1] + sc2[2][1] + sc2[3][1]) / Nf;
            out[0] = recon_f + kl_f - (diag / Nf) / sp;
        }
    }
}

extern "C" void kernel_launch(void* const* d_in, const int* in_sizes, int n_in,
                              void* d_out, int out_size, void* d_ws, size_t ws_size,
                              hipStream_t stream) {
    const f4v* target = (const f4v*)d_in[0];
    const f4v* output = (const f4v*)d_in[1];
    const f4v* mean   = (const f4v*)d_in[2];
    const f4v* logvar = (const f4v*)d_in[3];
    const f4v* zt     = (const f4v*)d_in[4];
    const f4v* ztau   = (const f4v*)d_in[5];
    float* ws  = (float*)d_ws;
    float* out = (float*)d_out;

    // zero Z replicas + ticket (ws re-poisoned to 0xAA each call)
    hipMemsetAsync(ws, 0, MEMSET_BYTES, stream);
    vde_fused<<<BLOCKS, THREADS, 0, stream>>>(target, output, mean, logvar, zt, ztau, ws, out);
}

// Round 7
// 151.631 us; speedup vs baseline: 3.2254x; 3.2254x over previous
//
#include <hip/hip_runtime.h>

// N=65536, D_OUT=128, D_LAT=64, D_Z=64. Streaming multi-reduction.
// R6 lesson (matches R2): a returning atomicAdd ticket on ONE address costs
// ~180ns x 2048 blocks ~ 370us (serialized cross-XCD ownership+return).
// Fire-and-forget atomics to 64 replicas pipeline fine. So: NO ticket;
// separate tiny tail kernel. Keep NT loads + hoisted loads + plain partial
// stores for MSE/KL.
constexpr int N_ROWS  = 65536;
constexpr int THREADS = 256;
constexpr int B_MSE = 1024, B_KL = 512, B_Z = 512;
constexpr int BLOCKS = B_MSE + B_KL + B_Z;      // 2048
constexpr int F4_BLK = 2048;                    // float4s per block per array
constexpr int IT     = F4_BLK / THREADS;        // 8 iters/thread

constexpr int NREP  = 64;                       // Z replicas: contention 512/64 = 8
constexpr int NZVAL = 320;                      // 5 stats x 64 cols
// ws layout (floats):
//   [r*NZVAL + v]        r in [0,64): Z replica accumulators (memset 0)
//   [MSE_OFF + b]        per-block MSE partial, b in [0,1024) (plain store)
//   [KL_OFF + i]         per-block KL partial, i in [0,512)  (plain store)
constexpr int MSE_OFF = NREP * NZVAL;           // 20480
constexpr int KL_OFF  = MSE_OFF + B_MSE;        // 21504
constexpr int MEMSET_BYTES = NREP * NZVAL * 4;  // only the Z replicas

typedef float f4v __attribute__((ext_vector_type(4)));

__device__ __forceinline__ f4v ntload(const f4v* p) {
    return __builtin_nontemporal_load(p);
}

__global__ __launch_bounds__(THREADS) void vde_main(
    const f4v* __restrict__ target,
    const f4v* __restrict__ output,
    const f4v* __restrict__ mean,
    const f4v* __restrict__ logvar,
    const f4v* __restrict__ zt,
    const f4v* __restrict__ ztau,
    float* __restrict__ ws)
{
    const int lane = threadIdx.x & 63;
    const int wave = threadIdx.x >> 6;

    __shared__ float ssc[4];                 // scalar cross-wave (MSE/KL)
    __shared__ float sred[4][16][20];        // column stats cross-wave (Z)

    if (blockIdx.x < B_MSE) {
        // ---------------- MSE: sum (o - t)^2 ------------------------------
        const int base = blockIdx.x * F4_BLK + threadIdx.x;
        f4v o[IT], t[IT];
        #pragma unroll
        for (int it = 0; it < IT; ++it) o[it] = ntload(&output[base + it * THREADS]);
        #pragma unroll
        for (int it = 0; it < IT; ++it) t[it] = ntload(&target[base + it * THREADS]);
        float recon = 0.f;
        #pragma unroll
        for (int it = 0; it < IT; ++it) {
            f4v d = o[it] - t[it];
            recon += d[0]*d[0] + d[1]*d[1] + d[2]*d[2] + d[3]*d[3];
        }
        #pragma unroll
        for (int m = 32; m >= 1; m >>= 1) recon += __shfl_xor(recon, m);
        if (lane == 0) ssc[wave] = recon;
        __syncthreads();
        if (threadIdx.x == 0)
            ws[MSE_OFF + blockIdx.x] = ssc[0] + ssc[1] + ssc[2] + ssc[3];

    } else if (blockIdx.x < B_MSE + B_KL) {
        // ---------------- KL: sum (lv - e^lv - m^2 + 1) -------------------
        const int bi = blockIdx.x - B_MSE;
        const int base = bi * F4_BLK + threadIdx.x;
        f4v lv[IT], mm[IT];
        #pragma unroll
        for (int it = 0; it < IT; ++it) lv[it] = ntload(&logvar[base + it * THREADS]);
        #pragma unroll
        for (int it = 0; it < IT; ++it) mm[it] = ntload(&mean[base + it * THREADS]);
        float kls = 0.f;
        #pragma unroll
        for (int it = 0; it < IT; ++it) {
            kls += (lv[it][0] - __expf(lv[it][0]) - mm[it][0]*mm[it][0] + 1.f)
                 + (lv[it][1] - __expf(lv[it][1]) - mm[it][1]*mm[it][1] + 1.f)
                 + (lv[it][2] - __expf(lv[it][2]) - mm[it][2]*mm[it][2] + 1.f)
                 + (lv[it][3] - __expf(lv[it][3]) - mm[it][3]*mm[it][3] + 1.f);
        }
        #pragma unroll
        for (int m = 32; m >= 1; m >>= 1) kls += __shfl_xor(kls, m);
        if (lane == 0) ssc[wave] = kls;
        __syncthreads();
        if (threadIdx.x == 0)
            ws[KL_OFF + bi] = ssc[0] + ssc[1] + ssc[2] + ssc[3];

    } else {
        // ---------------- Z column stats ----------------------------------
        // f = zb*2048 + it*256 + tid -> f%16 == tid%16: each thread owns the
        // fixed 4-column group g = tid&15 (cols 4g..4g+3).
        const int zi = blockIdx.x - B_MSE - B_KL;
        const int base = zi * F4_BLK + threadIdx.x;
        f4v a[IT], b[IT];
        #pragma unroll
        for (int it = 0; it < IT; ++it) a[it] = ntload(&zt[base + it * THREADS]);
        #pragma unroll
        for (int it = 0; it < IT; ++it) b[it] = ntload(&ztau[base + it * THREADS]);
        float s_t[4] = {0,0,0,0}, s_t2[4] = {0,0,0,0};
        float s_a[4] = {0,0,0,0}, s_a2[4] = {0,0,0,0}, s_c[4] = {0,0,0,0};
        #pragma unroll
        for (int it = 0; it < IT; ++it) {
            #pragma unroll
            for (int e = 0; e < 4; ++e) {
                s_t[e]  += a[it][e];          s_a[e]  += b[it][e];
                s_t2[e] += a[it][e]*a[it][e]; s_a2[e] += b[it][e]*b[it][e];
                s_c[e]  += a[it][e]*b[it][e];
            }
        }
        float vals[20];
        #pragma unroll
        for (int e = 0; e < 4; ++e) {
            vals[e*5+0] = s_t[e];  vals[e*5+1] = s_a[e];
            vals[e*5+2] = s_t2[e]; vals[e*5+3] = s_a2[e];
            vals[e*5+4] = s_c[e];
        }
        #pragma unroll
        for (int v = 0; v < 20; ++v) {
            vals[v] += __shfl_xor(vals[v], 16);
            vals[v] += __shfl_xor(vals[v], 32);
        }
        if (lane < 16) {
            #pragma unroll
            for (int v = 0; v < 20; ++v) sred[wave][lane][v] = vals[v];
        }
        __syncthreads();
        float* rep = ws + (zi & (NREP - 1)) * NZVAL;
        for (int i = threadIdx.x; i < 320; i += THREADS) {
            const int g = i / 20, v = i % 20;
            const float s = sred[0][g][v] + sred[1][g][v]
                          + sred[2][g][v] + sred[3][g][v];
            const int e = v / 5, st = v % 5;
            atomicAdd(&rep[st * 64 + (g * 4 + e)], s);  // no return -> pipelines
        }
    }
}

// Collapse replicas + per-block partials + finalize. One block.
__global__ __launch_bounds__(256) void vde_tail(
    const float* __restrict__ ws, float* __restrict__ out)
{
    // Z replicas: value v summed over 64 replicas (coalesced in v)
    __shared__ float zsums[NZVAL];
    for (int v = threadIdx.x; v < NZVAL; v += 256) {
        float s = 0.f;
        #pragma unroll 8
        for (int r = 0; r < NREP; ++r) s += ws[r * NZVAL + v];
        zsums[v] = s;
    }
    // MSE / KL per-block partials
    float rsum = 0.f;
    for (int i = threadIdx.x; i < B_MSE; i += 256) rsum += ws[MSE_OFF + i];
    float ksum = 0.f;
    for (int i = threadIdx.x; i < B_KL; i += 256) ksum += ws[KL_OFF + i];
    #pragma unroll
    for (int m = 32; m >= 1; m >>= 1) {
        rsum += __shfl_xor(rsum, m);
        ksum += __shfl_xor(ksum, m);
    }
    __shared__ float sc2[4][2];
    const int lane = threadIdx.x & 63;
    const int wave = threadIdx.x >> 6;
    if (lane == 0) { sc2[wave][0] = rsum; sc2[wave][1] = ksum; }
    __syncthreads();

    if (threadIdx.x < 64) {
        const int j = threadIdx.x;          // column 0..63
        const float Nf = (float)N_ROWS;
        const float sum_t  = zsums[0*64 + j];
        const float sum_a  = zsums[1*64 + j];
        const float sum_t2 = zsums[2*64 + j];
        const float sum_a2 = zsums[3*64 + j];
        const float sum_c  = zsums[4*64 + j];

        const float mu_t = sum_t / Nf, mu_a = sum_a / Nf;
        float diag = sum_c - Nf * mu_t * mu_a;
        const float var_t = (sum_t2 - Nf * mu_t * mu_t) / (Nf - 1.f);
        const float var_a = (sum_a2 - Nf * mu_a * mu_a) / (Nf - 1.f);
        float sp = sqrtf(var_t) * sqrtf(var_a);

        #pragma unroll
        for (int m = 32; m >= 1; m >>= 1) {
            diag += __shfl_xor(diag, m);
            sp   += __shfl_xor(sp, m);
        }
        if (j == 0) {
            const float recon_f = (sc2[0][0] + sc2[1][0] + sc2[2][0] + sc2[3][0]) / (Nf * 128.f);
            const float kl_f    = -0.5f * (sc2[0][1] + sc2[1][1] + sc2[2][1] + sc2[3][1]) / Nf;
            out[0] = recon_f + kl_f - (diag / Nf) / sp;
        }
    }
}

extern "C" void kernel_launch(void* const* d_in, const int* in_sizes, int n_in,
                              void* d_out, int out_size, void* d_ws, size_t ws_size,
                              hipStream_t stream) {
    const f4v* target = (const f4v*)d_in[0];
    const f4v* output = (const f4v*)d_in[1];
    const f4v* mean   = (const f4v*)d_in[2];
    const f4v* logvar = (const f4v*)d_in[3];
    const f4v* zt     = (const f4v*)d_in[4];
    const f4v* ztau   = (const f4v*)d_in[5];
    float* ws  = (float*)d_ws;
    float* out = (float*)d_out;

    // zero only the Z replica accumulators (ws re-poisoned to 0xAA each call)
    hipMemsetAsync(ws, 0, MEMSET_BYTES, stream);
    vde_main<<<BLOCKS, THREADS, 0, stream>>>(target, output, mean, logvar, zt, ztau, ws);
    vde_tail<<<1, 256, 0, stream>>>(ws, out);
}